// Round 7
// baseline (437.919 us; speedup 1.0000x reference)
//
#include <hip/hip_runtime.h>
#include <hip/hip_bf16.h>

typedef __bf16 bf16_t;
typedef __bf16 bf16x4_t __attribute__((ext_vector_type(4)));
typedef __bf16 bf16x8 __attribute__((ext_vector_type(8)));
typedef float f32x16 __attribute__((ext_vector_type(16)));

#define EPS 0.5f
#define MFMA32(a, b, c) __builtin_amdgcn_mfma_f32_32x32x16_bf16(a, b, c, 0, 0, 0)

// ---------------- one-time weight conversion ----------------
// W1t [128 j][1024 i] bf16 (for gemm_A).
// W2B frag-major (C-pass A-operand): idx = ((jt*64+s)*64+lane)*8+e
//     element = W2[jt*32+(lane&31)][s*16+(lane>>5)*8+e]   (0 if k>=1000)
// W2T frag-major (D-pass A-operand): idx = ((kt*8+js)*64+lane)*8+e
//     element = W2[js*16+(lane>>5)*8+e][kt*32+(lane&31)]  (0 if k>=1000)
__global__ __launch_bounds__(256) void prep_weights(
    const float* __restrict__ W1, const float* __restrict__ W2,
    bf16_t* __restrict__ W1t, bf16_t* __restrict__ W2B, bf16_t* __restrict__ W2T) {
  int idx = blockIdx.x * 256 + threadIdx.x;
  if (idx < 131072) {
    { int j = idx >> 10, i = idx & 1023; W1t[idx] = (bf16_t)W1[i * 128 + j]; }
    { int e = idx & 7, l = (idx >> 3) & 63, s = (idx >> 9) & 63, jt = idx >> 15;
      int j = jt * 32 + (l & 31), k = s * 16 + (l >> 5) * 8 + e;
      W2B[idx] = (bf16_t)((k < 1000) ? W2[j * 1000 + k] : 0.f); }
    { int e = idx & 7, l = (idx >> 3) & 63, js = (idx >> 9) & 7, kt = idx >> 12;
      int k = kt * 32 + (l & 31), j = js * 16 + (l >> 5) * 8 + e;
      W2T[idx] = (bf16_t)((k < 1000) ? W2[j * 1000 + k] : 0.f); }
  }
}

// ---------------- A = x @ W1 (f32 out), bf16 MFMA (verified r1-r6) --------
__global__ __launch_bounds__(256) void gemm_A(
    const float* __restrict__ x, const bf16_t* __restrict__ W1t,
    float* __restrict__ A) {
  int lane = threadIdx.x & 63, w = threadIdx.x >> 6;
  int row0 = blockIdx.x * 64;
  int mt = w & 1, np = (w >> 1) * 2;
  f32x16 acc0 = {}, acc1 = {};
  int ar = row0 + mt * 32 + (lane & 31);
  int kg = (lane >> 5) * 8;
  const float* xrow = x + (size_t)ar * 1024 + kg;
  const bf16_t* b0 = W1t + ((np * 32 + (lane & 31)) << 10) + kg;
  const bf16_t* b1 = W1t + (((np + 1) * 32 + (lane & 31)) << 10) + kg;
#pragma unroll 4
  for (int ks = 0; ks < 64; ++ks) {
    float xv[8];
    *(float4*)&xv[0] = *(const float4*)(xrow + ks * 16);
    *(float4*)&xv[4] = *(const float4*)(xrow + ks * 16 + 4);
    bf16x8 a;
#pragma unroll
    for (int i = 0; i < 8; ++i) a[i] = (bf16_t)xv[i];
    bf16x8 f0 = *(const bf16x8*)(b0 + ks * 16);
    bf16x8 f1 = *(const bf16x8*)(b1 + ks * 16);
    acc0 = MFMA32(a, f0, acc0);
    acc1 = MFMA32(a, f1, acc1);
  }
#pragma unroll
  for (int reg = 0; reg < 16; ++reg) {
    int r = mt * 32 + (reg & 3) + 8 * (reg >> 2) + 4 * (lane >> 5);
    A[(size_t)(row0 + r) * 128 + np * 32 + (lane & 31)] = acc0[reg];
    A[(size_t)(row0 + r) * 128 + (np + 1) * 32 + (lane & 31)] = acc1[reg];
  }
}

// state update: n = clip(v - eps*rho'*(v - u)); JAX clip tie-grad 0.5 at {0,1}
__device__ __forceinline__ bf16x4_t upd4(bf16x4_t v4, const float* u) {
  bf16x4_t n4;
#pragma unroll
  for (int r = 0; r < 4; ++r) {
    float v = (float)v4[r];
    float g = __builtin_fmaf(v, v, -v);          // 0 iff v in {0,1}
    float st = (g == 0.f) ? 0.25f : 0.5f;        // eps * rho'
    float n = __builtin_fmaf(-st, v - u[r], v);
    n4[r] = (bf16_t)__builtin_amdgcn_fmed3f(n, 0.f, 1.f);
  }
  return n4;
}

// ---------------- persistent relaxation + log_softmax ----------------
// 256 blocks x 1024 threads (16 waves, 1 block/CU, 128-reg cap).
// State in LDS, fragment-major (frag s at s*1024 + lane*16): base+imm
// addressing. Waves 0-3 (C): Ct[32j,32b] full-K, 16 frags resident + 48
// streamed via unroll-1 parity loop. Waves 4-15 (D): 2-3 ktiles; ktile0
// resident, later ktiles prefetched one tile ahead (L2 latency hides under
// the previous tile's update VALU). Double-buffered state, ONE barrier/iter.
__global__ __launch_bounds__(1024, 4) void eqprop(
    const float* __restrict__ h0, const float* __restrict__ o0,
    const float* __restrict__ b_h, const float* __restrict__ b_o,
    const float* __restrict__ A, const bf16_t* __restrict__ W2B,
    const bf16_t* __restrict__ W2T, const int* __restrict__ nit,
    float* __restrict__ out) {
  __shared__ __align__(16) char o_raw[131072];  // 2 x 64 KB frag-major
  __shared__ __align__(16) char h_raw[16384];   // 2 x 8 KB frag-major
  __shared__ float bo_lds[1024];

  const int tid = threadIdx.x, lane = tid & 63, w = tid >> 6;
  const int lo = lane & 31, hi = lane >> 5;
  const int row0 = blockIdx.x * 32;

  // ---- init buffer 0 (frag-major) + bo table
  for (int idx = tid; idx < 32768; idx += 1024) {
    int b = idx >> 10, k = idx & 1023;
    float v = (k < 1000) ? o0[(size_t)(row0 + b) * 1000 + k] : 0.f;
    int ad = ((k >> 4) << 10) + ((((k >> 3) & 1) << 5) + b) * 16 + ((k & 7) << 1);
    *(bf16_t*)(o_raw + ad) = (bf16_t)v;
  }
  for (int idx = tid; idx < 4096; idx += 1024) {
    int b = idx >> 7, j = idx & 127;
    int ad = ((j >> 4) << 10) + ((((j >> 3) & 1) << 5) + b) * 16 + ((j & 7) << 1);
    *(bf16_t*)(h_raw + ad) = (bf16_t)h0[(size_t)(row0 + b) * 128 + j];
  }
  bo_lds[tid] = (tid < 1000) ? b_o[tid] : 0.f;

  const int T = nit[0];
  int p = 0;
  __syncthreads();

  if (w < 4) {
    // ============ C-waves: Ct[j,b] = sum_k W2[j,k] o[b,k], jt = w =========
    const int jt = w;
    const bf16_t* WB = W2B + (size_t)jt * 32768 + lane * 8;
#define CW(s) (*(const bf16x8*)(WB + (s) * 512))
    bf16x8 wres[16];
#pragma unroll
    for (int s = 0; s < 16; ++s) wres[s] = CW(s);
    const char* obase = o_raw + lane * 16;

    for (int t = 0; t < T; ++t) {
      const char* obP = obase + (p << 16);
#define OF(s) (*(const bf16x8*)(obP + (s) * 1024))
      f32x16 acc = {};
#pragma unroll
      for (int s = 0; s < 16; ++s) acc = MFMA32(wres[s], OF(s), acc);
      // streamed k-steps 16..63: unroll-1 parity loop (bounds liveness)
      bf16x8 cs0[4], cs1[4];
      cs0[0] = CW(16); cs0[1] = CW(17); cs0[2] = CW(18); cs0[3] = CW(19);
#pragma unroll 1
      for (int c = 0; c < 12; ++c) {
        const int s0 = 16 + c * 4;
        if ((c & 1) == 0) {
          if (c < 11) {
            cs1[0] = CW(s0 + 4); cs1[1] = CW(s0 + 5);
            cs1[2] = CW(s0 + 6); cs1[3] = CW(s0 + 7);
          }
          acc = MFMA32(cs0[0], OF(s0 + 0), acc);
          acc = MFMA32(cs0[1], OF(s0 + 1), acc);
          acc = MFMA32(cs0[2], OF(s0 + 2), acc);
          acc = MFMA32(cs0[3], OF(s0 + 3), acc);
        } else {
          if (c < 11) {
            cs0[0] = CW(s0 + 4); cs0[1] = CW(s0 + 5);
            cs0[2] = CW(s0 + 6); cs0[3] = CW(s0 + 7);
          }
          acc = MFMA32(cs1[0], OF(s0 + 0), acc);
          acc = MFMA32(cs1[1], OF(s0 + 1), acc);
          acc = MFMA32(cs1[2], OF(s0 + 2), acc);
          acc = MFMA32(cs1[3], OF(s0 + 3), acc);
        }
      }
      // ---- h-update: lane owns b=lo, j = jt*32 + q*8 + 4*hi + r
      const char* hrd = h_raw + (p << 13) + lo * 16 + hi * 8;
      char* hwr = h_raw + ((p ^ 1) << 13) + lo * 16 + hi * 8;
#pragma unroll
      for (int q = 0; q < 4; ++q) {
        const int jb = jt * 32 + q * 8 + 4 * hi;
        const int boff = (jt * 2 + (q >> 1)) * 1024 + (q & 1) * 512;
        float av[4], bh[4], u[4];
        *(float4*)av = *(const float4*)(A + (size_t)(row0 + lo) * 128 + jb);
        *(float4*)bh = *(const float4*)(b_h + jb);
#pragma unroll
        for (int r = 0; r < 4; ++r) u[r] = av[r] + bh[r] + acc[q * 4 + r];
        bf16x4_t v4 = *(const bf16x4_t*)(hrd + boff);
        *(bf16x4_t*)(hwr + boff) = upd4(v4, u);
      }
      __syncthreads();
      p ^= 1;
    }
  } else {
    // ============ D-waves: Dt[k,b] = sum_j W2[j,k] h[b,j] =================
    const int wd = w - 4;
    const int kt0 = (wd < 8) ? wd * 3 : 24 + (wd - 8) * 2;
    const int nkt = (wd < 8) ? 3 : 2;
    const bf16_t* WT = W2T + (size_t)kt0 * 4096 + lane * 8;
#define DW(f) (*(const bf16x8*)(WT + (f) * 512))
    bf16x8 wres[8];
#pragma unroll
    for (int f = 0; f < 8; ++f) wres[f] = DW(f);
    const char* hbase = h_raw + lane * 16;
    const char* obase = o_raw + lo * 16 + hi * 8;

    for (int t = 0; t < T; ++t) {
      const char* hbP = hbase + (p << 13);
      bf16x8 hf[8];
#pragma unroll
      for (int js = 0; js < 8; ++js)
        hf[js] = *(const bf16x8*)(hbP + js * 1024);
      const char* ord = obase + (p << 16);
      char* owr = o_raw + lo * 16 + hi * 8 + ((p ^ 1) << 16);

      // prefetch streamed ktile 1 (latency hides under kt0 MFMA + update)
      bf16x8 sw[8];
#pragma unroll
      for (int js = 0; js < 8; ++js) sw[js] = DW(8 + js);

      // ---- ktile 0 (resident weights)
      f32x16 acc = {};
#pragma unroll
      for (int js = 0; js < 8; ++js) acc = MFMA32(wres[js], hf[js], acc);
#pragma unroll
      for (int q = 0; q < 4; ++q) {
        const int boff = (kt0 * 2 + (q >> 1)) * 1024 + (q & 1) * 512;
        float bo4[4], u[4];
        *(float4*)bo4 = *(const float4*)(bo_lds + kt0 * 32 + q * 8 + 4 * hi);
#pragma unroll
        for (int r = 0; r < 4; ++r) u[r] = bo4[r] + acc[q * 4 + r];
        bf16x4_t v4 = *(const bf16x4_t*)(ord + boff);
        *(bf16x4_t*)(owr + boff) = upd4(v4, u);
      }

      // ---- streamed ktiles (1..nkt-1); refill sw one tile ahead
#pragma unroll 1
      for (int kl = 1; kl < nkt; ++kl) {
        const int kt = kt0 + kl;
        f32x16 a2 = {};
        a2 = MFMA32(sw[0], hf[0], a2);
        a2 = MFMA32(sw[1], hf[1], a2);
        a2 = MFMA32(sw[2], hf[2], a2);
        a2 = MFMA32(sw[3], hf[3], a2);
        a2 = MFMA32(sw[4], hf[4], a2);
        a2 = MFMA32(sw[5], hf[5], a2);
        a2 = MFMA32(sw[6], hf[6], a2);
        a2 = MFMA32(sw[7], hf[7], a2);
        if (kl + 1 < nkt) {
#pragma unroll
          for (int js = 0; js < 8; ++js) sw[js] = DW((kl + 1) * 8 + js);
        }
#pragma unroll
        for (int q = 0; q < 4; ++q) {
          const int boff = (kt * 2 + (q >> 1)) * 1024 + (q & 1) * 512;
          float bo4[4], u[4];
          *(float4*)bo4 = *(const float4*)(bo_lds + kt * 32 + q * 8 + 4 * hi);
#pragma unroll
          for (int r = 0; r < 4; ++r) u[r] = bo4[r] + a2[q * 4 + r];
          bf16x4_t v4 = *(const bf16x4_t*)(ord + boff);
          *(bf16x4_t*)(owr + boff) = upd4(v4, u);
        }
      }
      __syncthreads();
      p ^= 1;
    }
  }
  __syncthreads();

  // ---- epilogue: log_softmax per row (2 rows per wave)
  const char* of = o_raw + (p << 16);
  for (int row = w * 2; row < w * 2 + 2; ++row) {
    float m = -1e30f;
    for (int k = lane; k < 1000; k += 64) {
      int ad = ((k >> 4) << 10) + ((((k >> 3) & 1) << 5) + row) * 16 + ((k & 7) << 1);
      m = fmaxf(m, (float)*(const bf16_t*)(of + ad));
    }
#pragma unroll
    for (int s = 32; s > 0; s >>= 1) m = fmaxf(m, __shfl_xor(m, s));
    float sum = 0.f;
    for (int k = lane; k < 1000; k += 64) {
      int ad = ((k >> 4) << 10) + ((((k >> 3) & 1) << 5) + row) * 16 + ((k & 7) << 1);
      sum += expf((float)*(const bf16_t*)(of + ad) - m);
    }
#pragma unroll
    for (int s = 32; s > 0; s >>= 1) sum += __shfl_xor(sum, s);
    float lse = m + logf(sum);
    for (int k = lane; k < 1000; k += 64) {
      int ad = ((k >> 4) << 10) + ((((k >> 3) & 1) << 5) + row) * 16 + ((k & 7) << 1);
      out[(size_t)(row0 + row) * 1000 + k] =
          (float)*(const bf16_t*)(of + ad) - lse;
    }
  }
}

extern "C" void kernel_launch(void* const* d_in, const int* in_sizes, int n_in,
                              void* d_out, int out_size, void* d_ws, size_t ws_size,
                              hipStream_t stream) {
  const float* x   = (const float*)d_in[0];
  const float* h0  = (const float*)d_in[1];
  const float* o0  = (const float*)d_in[2];
  // d_in[3] = b_in: unused by the h/o gradients
  const float* b_h = (const float*)d_in[4];
  const float* b_o = (const float*)d_in[5];
  const float* W1  = (const float*)d_in[6];
  const float* W2  = (const float*)d_in[7];
  const int*   nit = (const int*)d_in[8];
  float* out = (float*)d_out;

  char* ws = (char*)d_ws;
  float*  A   = (float*)ws;                           // 8192*128*4 = 4 MB
  bf16_t* W1t = (bf16_t*)(ws + 4194304);              // 256 KB
  bf16_t* W2B = (bf16_t*)(ws + 4194304 + 262144);     // 256 KB
  bf16_t* W2T = (bf16_t*)(ws + 4194304 + 524288);     // 256 KB

  prep_weights<<<512, 256, 0, stream>>>(W1, W2, W1t, W2B, W2T);
  gemm_A<<<128, 256, 0, stream>>>(x, W1t, A);
  eqprop<<<256, 1024, 0, stream>>>(h0, o0, b_h, b_o, A, W2B, W2T, nit, out);
}

// Round 8
// 256.587 us; speedup vs baseline: 1.7067x; 1.7067x over previous
//
#include <hip/hip_runtime.h>
#include <hip/hip_bf16.h>

typedef __bf16 bf16_t;
typedef __bf16 bf16x4_t __attribute__((ext_vector_type(4)));
typedef __bf16 bf16x8 __attribute__((ext_vector_type(8)));
typedef float f32x16 __attribute__((ext_vector_type(16)));

#define EPS 0.5f
#define MFMA32(a, b, c) __builtin_amdgcn_mfma_f32_32x32x16_bf16(a, b, c, 0, 0, 0)

// 16-slot XOR swizzle (r4-proven). o rows: 2048 B; h rows: 256 B.
__device__ __forceinline__ int oswz(int row, int kbyte) {
  return (row << 11) + (kbyte ^ ((row & 15) << 4));
}
__device__ __forceinline__ int hswz(int row, int jbyte) {
  return (row << 8) + (jbyte ^ ((row & 15) << 4));
}

// ---------------- one-time weight conversion (verified r4-r7) -------------
__global__ __launch_bounds__(256) void prep_weights(
    const float* __restrict__ W1, const float* __restrict__ W2,
    bf16_t* __restrict__ W1t, bf16_t* __restrict__ W2B, bf16_t* __restrict__ W2T) {
  int idx = blockIdx.x * 256 + threadIdx.x;
  if (idx < 131072) {
    { int j = idx >> 10, i = idx & 1023; W1t[idx] = (bf16_t)W1[i * 128 + j]; }
    { int e = idx & 7, l = (idx >> 3) & 63, s = (idx >> 9) & 63, jt = idx >> 15;
      int j = jt * 32 + (l & 31), k = s * 16 + (l >> 5) * 8 + e;
      W2B[idx] = (bf16_t)((k < 1000) ? W2[j * 1000 + k] : 0.f); }
    { int e = idx & 7, l = (idx >> 3) & 63, js = (idx >> 9) & 7, kt = idx >> 12;
      int k = kt * 32 + (l & 31), j = js * 16 + (l >> 5) * 8 + e;
      W2T[idx] = (bf16_t)((k < 1000) ? W2[j * 1000 + k] : 0.f); }
  }
}

// ---------------- A = x @ W1, now 256 blocks (all CUs) --------------------
__global__ __launch_bounds__(256) void gemm_A(
    const float* __restrict__ x, const bf16_t* __restrict__ W1t,
    float* __restrict__ A) {
  int lane = threadIdx.x & 63, w = threadIdx.x >> 6;
  int lo = lane & 31, hi = lane >> 5;
  int row0 = blockIdx.x * 32;
  f32x16 acc = {};
  int kg = hi * 8;
  const float* xrow = x + (size_t)(row0 + lo) * 1024 + kg;
  const bf16_t* b0 = W1t + ((w * 32 + lo) << 10) + kg;
#pragma unroll 4
  for (int ks = 0; ks < 64; ++ks) {
    float xv[8];
    *(float4*)&xv[0] = *(const float4*)(xrow + ks * 16);
    *(float4*)&xv[4] = *(const float4*)(xrow + ks * 16 + 4);
    bf16x8 a;
#pragma unroll
    for (int i = 0; i < 8; ++i) a[i] = (bf16_t)xv[i];
    bf16x8 f0 = *(const bf16x8*)(b0 + ks * 16);
    acc = MFMA32(a, f0, acc);
  }
#pragma unroll
  for (int reg = 0; reg < 16; ++reg) {
    int r = (reg & 3) + 8 * (reg >> 2) + 4 * hi;
    A[(size_t)(row0 + r) * 128 + w * 32 + lo] = acc[reg];
  }
}

// state update: n = clip(v - eps*rho'*(v - u)); JAX clip tie-grad 0.5 at {0,1}
__device__ __forceinline__ bf16x4_t upd4(bf16x4_t v4, const float* u) {
  bf16x4_t n4;
#pragma unroll
  for (int r = 0; r < 4; ++r) {
    float v = (float)v4[r];
    float g = __builtin_fmaf(v, v, -v);          // 0 iff v in {0,1}
    float st = (g == 0.f) ? 0.25f : 0.5f;        // eps * rho'
    float n = __builtin_fmaf(-st, v - u[r], v);
    n4[r] = (bf16_t)__builtin_amdgcn_fmed3f(n, 0.f, 1.f);
  }
  return n4;
}

// ---------------- persistent relaxation + log_softmax ----------------
// r4 skeleton: 256 blocks x 1024 threads, double-buffered swizzled state,
// ONE barrier/iter. C-waves (0-3): full-K j-tile; 8 frags resident, 56
// streamed as 14x4 batches, 3-deep pipeline, block-rotated order.
// D-waves (4-15): r4-verbatim (12 resident frags, at-use streams).
__global__ __launch_bounds__(1024, 4) void eqprop(
    const float* __restrict__ h0, const float* __restrict__ o0,
    const float* __restrict__ b_h, const float* __restrict__ b_o,
    const float* __restrict__ A, const bf16_t* __restrict__ W2B,
    const bf16_t* __restrict__ W2T, const int* __restrict__ nit,
    float* __restrict__ out) {
  __shared__ __align__(16) char ob[2][65536];   // o state, swizzled bf16
  __shared__ __align__(16) char hb[2][8192];    // h state, swizzled bf16
  __shared__ float bo_lds[1024];

  const int tid = threadIdx.x, lane = tid & 63, w = tid >> 6;
  const int lo = lane & 31, hi = lane >> 5;
  const int row0 = blockIdx.x * 32;

  // ---- init state buffers [0] and b_o table (r4-verbatim)
  for (int idx = tid; idx < 32 * 1024; idx += 1024) {
    int r = idx >> 10, k = idx & 1023;
    float v = (k < 1000) ? o0[(size_t)(row0 + r) * 1000 + k] : 0.f;
    *(bf16_t*)(&ob[0][0] + oswz(r, k * 2)) = (bf16_t)v;
  }
  for (int idx = tid; idx < 32 * 128; idx += 1024) {
    int r = idx >> 7, j = idx & 127;
    *(bf16_t*)(&hb[0][0] + hswz(r, j * 2)) = (bf16_t)h0[(size_t)(row0 + r) * 128 + j];
  }
  bo_lds[tid] = (tid < 1000) ? b_o[tid] : 0.f;

  const int T = nit[0];
  int p = 0;
  __syncthreads();

  if (w < 4) {
    // ============ C-waves: Ct[j,b] = sum_k W2[j,k] o[b,k], jt = w =========
    const int jt = w;
    const bf16_t* WB = W2B + (size_t)jt * 32768 + lane * 8;
#define CW(s) (*(const bf16x8*)(WB + (size_t)(s) * 512))
    bf16x8 wres[8];
#pragma unroll
    for (int s = 0; s < 8; ++s) wres[s] = CW(s);
    const int rot = blockIdx.x % 14;   // per-block stream-order rotation

    for (int t = 0; t < T; ++t) {
      const char* op = &ob[p][0];
      f32x16 acc = {};
#pragma unroll
      for (int s = 0; s < 8; ++s) {
        bf16x8 of = *(const bf16x8*)(op + oswz(lo, s * 32 + hi * 16));
        acc = MFMA32(wres[s], of, acc);
      }
      // 56 streamed k-steps (8..63) = 14 batches of 4, rotated order,
      // 3-deep staging: consume batch q while batch q+2 is in flight.
      bf16x8 sA[4], sB[4], sC[4];
      int bq = rot;                              // batch being consumed
      int bl = rot + 2; if (bl >= 14) bl -= 14;  // batch being loaded
#define LOADB(ST, b) { const int s_ = 8 + (b) * 4; \
  ST[0] = CW(s_); ST[1] = CW(s_ + 1); ST[2] = CW(s_ + 2); ST[3] = CW(s_ + 3); }
#define CONSUME(ST) { const int s_ = 8 + bq * 4; \
  bf16x8 o0_ = *(const bf16x8*)(op + oswz(lo, s_ * 32 + hi * 16)); \
  acc = MFMA32(ST[0], o0_, acc); \
  bf16x8 o1_ = *(const bf16x8*)(op + oswz(lo, (s_ + 1) * 32 + hi * 16)); \
  acc = MFMA32(ST[1], o1_, acc); \
  bf16x8 o2_ = *(const bf16x8*)(op + oswz(lo, (s_ + 2) * 32 + hi * 16)); \
  acc = MFMA32(ST[2], o2_, acc); \
  bf16x8 o3_ = *(const bf16x8*)(op + oswz(lo, (s_ + 3) * 32 + hi * 16)); \
  acc = MFMA32(ST[3], o3_, acc); \
  bq += 1; if (bq >= 14) bq -= 14; }
      {
        int b1 = rot + 1; if (b1 >= 14) b1 -= 14;
        LOADB(sA, bq); LOADB(sB, b1);
      }
#pragma unroll 1
      for (int cc = 0; cc < 4; ++cc) {
        LOADB(sC, bl); bl += 1; if (bl >= 14) bl -= 14;
        CONSUME(sA);
        LOADB(sA, bl); bl += 1; if (bl >= 14) bl -= 14;
        CONSUME(sB);
        LOADB(sB, bl); bl += 1; if (bl >= 14) bl -= 14;
        CONSUME(sC);
      }
      CONSUME(sA);
      CONSUME(sB);

      // ---- h-update: lane owns b=lo, j = jt*32 + q*8 + 4*hi + r
      const char* hp = &hb[p][0];
      char* hn = &hb[p ^ 1][0];
#pragma unroll
      for (int q = 0; q < 4; ++q) {
        const int jb = jt * 32 + q * 8 + 4 * hi;
        float av[4], bh[4], u[4];
        *(float4*)av = *(const float4*)(A + (size_t)(row0 + lo) * 128 + jb);
        *(float4*)bh = *(const float4*)(b_h + jb);
#pragma unroll
        for (int r = 0; r < 4; ++r) u[r] = av[r] + bh[r] + acc[q * 4 + r];
        bf16x4_t v4 = *(const bf16x4_t*)(hp + hswz(lo, jb * 2));
        *(bf16x4_t*)(hn + hswz(lo, jb * 2)) = upd4(v4, u);
      }
      __syncthreads();
      p ^= 1;
    }
  } else {
    // ============ D-waves: Dt[k,b] = sum_j W2[j,k] h[b,j] (r4-verbatim) ===
    const int wd = w - 4;
    const int kt0 = (wd < 8) ? wd * 3 : 24 + (wd - 8) * 2;
    const int nkt = (wd < 8) ? 3 : 2;
    const bf16_t* WT = W2T + (size_t)kt0 * 4096 + lane * 8;
#define DW(f) (*(const bf16x8*)(WT + (size_t)(f) * 512))
    bf16x8 wres[12];   // ktile0 frags 0-7, ktile1 frags 8-11
#pragma unroll
    for (int f = 0; f < 12; ++f) wres[f] = DW(f);

    for (int t = 0; t < T; ++t) {
      const char* hp = &hb[p][0];
      const char* op = &ob[p][0];
      char* on = &ob[p ^ 1][0];
      bf16x8 hf[8];
#pragma unroll
      for (int kk = 0; kk < 8; ++kk)
        hf[kk] = *(const bf16x8*)(hp + hswz(lo, kk * 32 + hi * 16));

#pragma unroll 1
      for (int kl = 0; kl < nkt; ++kl) {
        const int kt = kt0 + kl;
        f32x16 acc = {};
        if (kl == 0) {
#pragma unroll
          for (int js = 0; js < 8; ++js) acc = MFMA32(wres[js], hf[js], acc);
        } else if (kl == 1) {
          bf16x8 s0 = DW(12), s1 = DW(13), s2 = DW(14), s3 = DW(15);
#pragma unroll
          for (int js = 0; js < 4; ++js)
            acc = MFMA32(wres[8 + js], hf[js], acc);
          acc = MFMA32(s0, hf[4], acc);
          acc = MFMA32(s1, hf[5], acc);
          acc = MFMA32(s2, hf[6], acc);
          acc = MFMA32(s3, hf[7], acc);
        } else {
          bf16x8 s0 = DW(16), s1 = DW(17), s2 = DW(18), s3 = DW(19);
          acc = MFMA32(s0, hf[0], acc);
          acc = MFMA32(s1, hf[1], acc);
          acc = MFMA32(s2, hf[2], acc);
          acc = MFMA32(s3, hf[3], acc);
          bf16x8 s4 = DW(20), s5 = DW(21), s6 = DW(22), s7 = DW(23);
          acc = MFMA32(s4, hf[4], acc);
          acc = MFMA32(s5, hf[5], acc);
          acc = MFMA32(s6, hf[6], acc);
          acc = MFMA32(s7, hf[7], acc);
        }
        // ---- o-update: lane owns b=lo, k = kt*32 + q*8 + 4*hi + r
#pragma unroll
        for (int q = 0; q < 4; ++q) {
          const int kb = kt * 32 + q * 8 + 4 * hi;
          float bo4[4], u[4];
          *(float4*)bo4 = *(const float4*)(bo_lds + kb);
#pragma unroll
          for (int r = 0; r < 4; ++r) u[r] = bo4[r] + acc[q * 4 + r];
          bf16x4_t v4 = *(const bf16x4_t*)(op + oswz(lo, kb * 2));
          *(bf16x4_t*)(on + oswz(lo, kb * 2)) = upd4(v4, u);
        }
      }
      __syncthreads();
      p ^= 1;
    }
  }
  __syncthreads();

  // ---- epilogue: log_softmax per row (2 rows per wave), r4-verbatim
  const char* of = &ob[p][0];
  for (int r = w * 2; r < w * 2 + 2; ++r) {
    float m = -1e30f;
    for (int k = lane; k < 1000; k += 64)
      m = fmaxf(m, (float)*(const bf16_t*)(of + oswz(r, k * 2)));
#pragma unroll
    for (int s = 32; s > 0; s >>= 1) m = fmaxf(m, __shfl_xor(m, s));
    float sum = 0.f;
    for (int k = lane; k < 1000; k += 64)
      sum += expf((float)*(const bf16_t*)(of + oswz(r, k * 2)) - m);
#pragma unroll
    for (int s = 32; s > 0; s >>= 1) sum += __shfl_xor(sum, s);
    float lse = m + logf(sum);
    for (int k = lane; k < 1000; k += 64)
      out[(size_t)(row0 + r) * 1000 + k] =
          (float)*(const bf16_t*)(of + oswz(r, k * 2)) - lse;
  }
}

extern "C" void kernel_launch(void* const* d_in, const int* in_sizes, int n_in,
                              void* d_out, int out_size, void* d_ws, size_t ws_size,
                              hipStream_t stream) {
  const float* x   = (const float*)d_in[0];
  const float* h0  = (const float*)d_in[1];
  const float* o0  = (const float*)d_in[2];
  // d_in[3] = b_in: unused by the h/o gradients
  const float* b_h = (const float*)d_in[4];
  const float* b_o = (const float*)d_in[5];
  const float* W1  = (const float*)d_in[6];
  const float* W2  = (const float*)d_in[7];
  const int*   nit = (const int*)d_in[8];
  float* out = (float*)d_out;

  char* ws = (char*)d_ws;
  float*  A   = (float*)ws;                           // 8192*128*4 = 4 MB
  bf16_t* W1t = (bf16_t*)(ws + 4194304);              // 256 KB
  bf16_t* W2B = (bf16_t*)(ws + 4194304 + 262144);     // 256 KB
  bf16_t* W2T = (bf16_t*)(ws + 4194304 + 524288);     // 256 KB

  prep_weights<<<512, 256, 0, stream>>>(W1, W2, W1t, W2B, W2T);
  gemm_A<<<256, 256, 0, stream>>>(x, W1t, A);
  eqprop<<<256, 1024, 0, stream>>>(h0, o0, b_h, b_o, A, W2B, W2T, nit, out);
}